// Round 13
// baseline (364.047 us; speedup 1.0000x reference)
//
#include <hip/hip_runtime.h>
#include <math.h>

#define NN 32768
#define NE 524288

typedef __attribute__((ext_vector_type(8))) short short8v;
typedef __attribute__((ext_vector_type(4))) float f32x4;

__device__ __forceinline__ float siluf(float x){
  return x * __builtin_amdgcn_rcpf(1.0f + __expf(-x));
}

__device__ __forceinline__ unsigned short f2bf(float x){
  unsigned int b = __float_as_uint(x);
  unsigned int r = ((b >> 16) & 1u) + 0x7fffu;
  return (unsigned short)((b + r) >> 16);
}

__device__ __forceinline__ unsigned int pk2(float a, float b){
  return (unsigned int)f2bf(a) | ((unsigned int)f2bf(b) << 16);
}

__device__ __forceinline__ float bf2f(unsigned short v){
  return __uint_as_float(((unsigned int)v) << 16);
}

__device__ __forceinline__ void unp4(uint2 u, float* x){
  x[0] = __uint_as_float(u.x << 16);
  x[1] = __uint_as_float(u.x & 0xffff0000u);
  x[2] = __uint_as_float(u.y << 16);
  x[3] = __uint_as_float(u.y & 0xffff0000u);
}

// Real-basis CG structural-nonzero mask (superset-safe selection rules).
__device__ __host__ constexpr bool cg_nz(int l1,int l2,int l3,int i,int j,int k){
  int m1=i-l1, m2=j-l2, m3=k-l3;
  int a1=m1<0?-m1:m1, a2=m2<0?-m2:m2, a3=m3<0?-m3:m3;
  int neg=(m1<0?1:0)+(m2<0?1:0)+(m3<0?1:0);
  bool par=(neg&1)==0;
  bool mag=(a3==a1+a2)||(a3==a1-a2)||(a3==a2-a1);
  return par&&mag;
}
__device__ __host__ constexpr bool m_nz(int l1,int l2,int l3,int i,int k){
  for(int j=0;j<2*l2+1;++j) if(cg_nz(l1,l2,l3,i,j,k)) return true;
  return false;
}

__device__ const int d_PL1[11] = {0,1,2,0,1,1,2,0,1,2,2};
__device__ const int d_PL2[11] = {0,1,2,1,0,2,1,2,1,0,2};
__device__ const int d_PL3[11] = {0,0,0,1,1,1,1,2,2,2,2};

// ---------------------------------------------------------------------------
// CG math (1/PATH_NORM folded).
// ---------------------------------------------------------------------------
__device__ double factd(int n){ double r=1.0; for(int i=2;i<=n;++i) r*=(double)i; return r; }

__device__ double su2_elem(int l1,int l2,int l3,int m1,int m2){
  int m3=m1+m2;
  if (m3 < -l3 || m3 > l3) return 0.0;
  double pref = sqrt((double)(2*l3+1)*factd(l3+l1-l2)*factd(l3-l1+l2)*factd(l1+l2-l3)/factd(l1+l2+l3+1));
  pref *= sqrt(factd(l3+m3)*factd(l3-m3)*factd(l1-m1)*factd(l1+m1)*factd(l2-m2)*factd(l2+m2));
  double s=0.0;
  for (int k=0;k<=l1+l2-l3;++k){
    int t1=l1+l2-l3-k, t2=l1-m1-k, t3=l2+m2-k, t4=l3-l2+m1+k, t5=l3-l1-m2+k;
    if (t1<0||t2<0||t3<0||t4<0||t5<0) continue;
    double d = factd(k)*factd(t1)*factd(t2)*factd(t3)*factd(t4)*factd(t5);
    s += ((k&1)? -1.0:1.0)/d;
  }
  return pref*s;
}

__device__ void q_elem(int l,int a,int i,double& re,double& im){
  re=0.0; im=0.0;
  const double is2 = 0.7071067811865476;
  int m = a - l;
  if (m==0){ if (i==l) re=1.0; return; }
  if (m>0){
    if (i==l+m)      re = (m&1)? -is2: is2;
    else if (i==l-m) re = is2;
  } else {
    int mm=-m;
    if (i==l-mm)      im = is2;
    else if (i==l+mm) im = (mm&1)? is2 : -is2;
  }
}

// ---------------------------------------------------------------------------
// init kernel: blocks 0..10 = CG table; blocks 11..78 = weight packing.
// Wm0p: B-frag order, K padded 8->32 with zeros, 1/sqrt(8) scale folded.
// ---------------------------------------------------------------------------
__global__ void init_kernel(const float* __restrict__ Wm0,
                            const float* __restrict__ Wm1,
                            const float* __restrict__ Wm2,
                            float* __restrict__ cgout,
                            unsigned short* __restrict__ Wm0p,
                            unsigned short* __restrict__ Wm1p,
                            unsigned short* __restrict__ Wm2p)
{
  if (blockIdx.x < 11){
    int p = blockIdx.x;
    int t = threadIdx.x;
    if (t >= 125) return;
    int a = t/25, b = (t/5)%5, c = t%5;
    int l1=d_PL1[p], l2=d_PL2[p], l3=d_PL3[p];
    int n1=2*l1+1, n2=2*l2+1, n3=2*l3+1;
    float outv = 0.0f;
    if (a<n1 && b<n2 && c<n3){
      double acc = 0.0;
      for (int i=0;i<n1;++i)
        for (int j=0;j<n2;++j){
          int m1=i-l1, m2=j-l2;
          int m3=m1+m2;
          if (m3 < -l3 || m3 > l3) continue;
          double cv = su2_elem(l1,l2,l3,m1,m2);
          if (cv==0.0) continue;
          int k = m3 + l3;
          double a1r,a1i,a2r,a2i,a3r,a3i;
          q_elem(l1,a,i,a1r,a1i);
          q_elem(l2,b,j,a2r,a2i);
          q_elem(l3,c,k,a3r,a3i);
          double re = (a1r*a2r - a1i*a2i)*a3r + (a1r*a2i + a1i*a2r)*a3i;
          acc += cv*re;
        }
      double invn = (l3==0)? 0.5773502691896258 : 0.5;
      outv = (float)(acc*invn);
    }
    cgout[p*125 + (a*5+b)*5 + c] = outv;
  } else {
    int t = (blockIdx.x - 11)*256 + threadIdx.x;
    if (t < 4096){
      int j = t & 7, lane = (t>>3)&63, ks = (t>>9)&1, ni = t>>10;
      int k = ks*32 + (lane>>4)*8 + j;
      int col = ni*16 + (lane&15);
      Wm1p[t] = f2bf(Wm1[k*64+col]);
    }
    int t2 = t - 4096;
    if (t2 >= 0 && t2 < 11264){
      int j = t2 & 7, lane = (t2>>3)&63, ks = (t2>>9)&1, ni = t2>>10;
      int k = ks*32 + (lane>>4)*8 + j;
      int col = ni*16 + (lane&15);
      Wm2p[t2] = f2bf(Wm2[k*176+col]);
    }
    int t3 = t - 15360;
    if (t3 >= 0 && t3 < 2048){
      int j = t3 & 7, lane = (t3>>3)&63, ni = t3>>9;
      int k = (lane>>4)*8 + j;       // K in [0,32), real only k<8
      int col = ni*16 + (lane&15);
      Wm0p[t3] = (k < 8) ? f2bf(Wm0[k*64+col]*0.3535533906f) : (unsigned short)0;
    }
  }
}

// ---------------------------------------------------------------------------
// Node up-projection -> bf16, iu-major layout (scaled 0.25).
// ---------------------------------------------------------------------------
__global__ __launch_bounds__(256) void node_up_kernel(
    const float* __restrict__ nf,
    const float* __restrict__ W0,
    const float* __restrict__ W1,
    const float* __restrict__ W2,
    unsigned short* __restrict__ mtabh)
{
  int gidx = blockIdx.x*256 + threadIdx.x;
  if (gidx >= NN*144) return;
  int n = gidx/144;
  int col = gidx - n*144;
  const float* f = nf + (size_t)n*144;
  float acc = 0.f;
  if (col < 16){
    int o = col;
    #pragma unroll
    for (int c=0;c<16;++c) acc += f[c]*W0[c*16+o];
  } else if (col < 64){
    int idx = col-16;
    int iu = idx >> 4, o = idx & 15;
    #pragma unroll
    for (int c=0;c<16;++c) acc += f[16+c*3+iu]*W1[c*16+o];
  } else {
    int idx = col-64;
    int iu = idx >> 4, o = idx & 15;
    #pragma unroll
    for (int c=0;c<16;++c) acc += f[64+c*5+iu]*W2[c*16+o];
  }
  mtabh[gidx] = f2bf(0.25f*acc);
}

// ---------------------------------------------------------------------------
// CSR build
// ---------------------------------------------------------------------------
__global__ __launch_bounds__(256) void hist_kernel(
    const int* __restrict__ recv, int* __restrict__ counts)
{
  int e = blockIdx.x*256 + threadIdx.x;
  if (e < NE) atomicAdd(&counts[recv[e]], 1);
}

__global__ __launch_bounds__(1024) void scan_kernel(
    const int* __restrict__ counts, int* __restrict__ offsets,
    int* __restrict__ nb, int NC)
{
  __shared__ int part[1024];
  int t = threadIdx.x;
  int local[32];
  int s = 0;
  #pragma unroll
  for (int i=0;i<32;++i){ local[i]=counts[t*32+i]; s+=local[i]; }
  part[t]=s;
  __syncthreads();
  for (int off=1; off<1024; off<<=1){
    int v = (t>=off)? part[t-off] : 0;
    __syncthreads();
    part[t] += v;
    __syncthreads();
  }
  int base = part[t] - s;
  int run = base;
  #pragma unroll
  for (int i=0;i<32;++i){ offsets[t*32+i]=run; run+=local[i]; }
  if (t==1023) offsets[NN]=run;

  for (int i=1; i<NC; ++i){
    long long Ti = (long long)NE*i/NC;
    if ((long long)base <= Ti && Ti < (long long)part[t]){
      int run2 = base;
      #pragma unroll
      for (int k=0;k<32;++k){
        int nxt = run2 + local[k];
        if (run2 <= Ti && Ti < nxt) nb[i] = t*32 + k + 1;
        run2 = nxt;
      }
    }
  }
  if (t==0) nb[0]=0;
  if (t==1023) nb[NC]=NN;
}

__global__ __launch_bounds__(256) void scatter_kernel(
    const int* __restrict__ recv, const int* __restrict__ offsets,
    int* __restrict__ cursor, int* __restrict__ edge_sorted)
{
  int e = blockIdx.x*256 + threadIdx.x;
  if (e < NE){
    int r = recv[e];
    int pos = atomicAdd(&cursor[r], 1);
    edge_sorted[offsets[r] + pos] = e;
  }
}

// ---------------------------------------------------------------------------
// Edge MLP + mix, all three GEMMs on MFMA. Emits mixb planes + side data.
// ---------------------------------------------------------------------------
__global__ __launch_bounds__(256) void edge_mix_kernel(
    const float* __restrict__ vectors,
    const int* __restrict__ senders,
    const int* __restrict__ edge_sorted,
    const int* __restrict__ offsets,
    const int* __restrict__ nb,
    const unsigned short* __restrict__ Wm0p,
    const unsigned short* __restrict__ Wm1p,
    const unsigned short* __restrict__ Wm2p,
    int ci, int plane_stride,
    unsigned short* __restrict__ mixb,
    unsigned short* __restrict__ ylm,
    int* __restrict__ sedge)
{
  __shared__ unsigned short lds_h[4][8*64*8];
  __shared__ float lds_s[4][64];

  int sbase = offsets[nb[ci]];
  int nE = offsets[nb[ci+1]] - sbase;
  int tid = threadIdx.x;
  int wid = tid >> 6;
  int lane = tid & 63;
  int g = lane >> 4;
  int l15 = lane & 15;
  int wb = blockIdx.x*256 + wid*64;
  int slot = wb + lane;

  float vx=0.f, vy=0.f, vz=0.f;
  int snd = 0;
  if (slot < nE){
    int e = edge_sorted[sbase + slot];
    vx = vectors[(size_t)e*3+0];
    vy = vectors[(size_t)e*3+1];
    vz = vectors[(size_t)e*3+2];
    snd = senders[e];
  }
  float r = sqrtf(vx*vx + vy*vy + vz*vz);
  float safe = (r > 1e-9f) ? r : 1.0f;
  float inv_safe = 1.0f/safe;

  const float PIf = 3.14159265358979f;
  float xc = fminf(r*0.25f, 1.0f);
  float s1 = __sinf(PIf*xc);
  float c1 = __cosf(PIf*xc);
  float env = 0.5f*(c1 + 1.0f);
  float pref = 0.70710678118f * env * inv_safe;
  float rb[8];
  {
    float sk=s1, ck=c1;
    rb[0]=pref*sk;
    #pragma unroll
    for (int k=1;k<8;++k){
      float sn = sk*c1 + ck*s1;
      float cn = ck*c1 - sk*s1;
      sk=sn; ck=cn;
      rb[k]=pref*sk;
    }
  }

  if (slot < nE){
    float ux=vx*inv_safe, uy=vy*inv_safe, uz=vz*inv_safe;
    const float SQ3  = 1.73205080757f;
    const float SQ15 = 3.87298334621f;
    union { uint4 u; unsigned short s[8]; } yv;
    yv.s[0]=f2bf(SQ3*uy);  yv.s[1]=f2bf(SQ3*uz);  yv.s[2]=f2bf(SQ3*ux);
    yv.s[3]=f2bf(SQ15*ux*uy);
    yv.s[4]=f2bf(SQ15*uy*uz);
    yv.s[5]=f2bf(1.11803398875f*(3.f*uz*uz-1.f));
    yv.s[6]=f2bf(SQ15*ux*uz);
    yv.s[7]=f2bf(1.93649167310f*(ux*ux-uy*uy));
    *(uint4*)(ylm + (size_t)slot*8) = yv.u;
    sedge[slot] = snd;
  }

  unsigned short* Lh = lds_h[wid];

  // rb -> bf16 LDS [64 rows][8] (first 1 KB of Lh)
  {
    union { uint4 u; unsigned short s[8]; } rv;
    #pragma unroll
    for (int k=0;k<8;++k) rv.s[k]=f2bf(rb[k]);
    *(uint4*)(Lh + (size_t)lane*8) = rv.u;
  }
  lds_s[wid][lane] = (r == 0.0f) ? 0.0f : 0.125f;

  __syncthreads();

  // ---- layer 1 via MFMA: h = silu( rb @ (Wm0/sqrt8) ) -> Lh [c][row][8] ----
  short8v a1[4];
  {
    short8v zz = {0,0,0,0,0,0,0,0};
    #pragma unroll
    for (int mi=0;mi<4;++mi){
      short8v av = *(short8v*)(Lh + (size_t)(mi*16 + l15)*8);
      a1[mi] = (g==0) ? av : zz;
    }
  }
  #pragma unroll
  for (int ni=0;ni<4;++ni){
    short8v b = *(short8v*)(Wm0p + ((size_t)(ni*64 + lane))*8);
    #pragma unroll
    for (int mi=0;mi<4;++mi){
      f32x4 acc = {0.f,0.f,0.f,0.f};
      acc = __builtin_amdgcn_mfma_f32_16x16x32_bf16(a1[mi], b, acc, 0,0,0);
      int col = ni*16 + l15;
      int c = col >> 3, cb = col & 7;
      #pragma unroll
      for (int reg=0;reg<4;++reg){
        int row = mi*16 + g*4 + reg;
        Lh[((size_t)(c*64 + row))*8 + cb] = f2bf(siluf(acc[reg]));
      }
    }
  }

  __syncthreads();

  // ---- layer 2: h2 = silu((h @ Wm1)/8) via MFMA, back into Lh ----
  short8v a[8];
  #pragma unroll
  for (int mi=0;mi<4;++mi){
    #pragma unroll
    for (int ks=0;ks<2;++ks)
      a[mi*2+ks] = *(short8v*)(Lh + ((size_t)((ks*4+g)*64 + mi*16 + l15))*8);
  }
  #pragma unroll 1
  for (int ni=0;ni<4;++ni){
    short8v b0 = *(short8v*)(Wm1p + ((size_t)((ni*2+0)*64 + lane))*8);
    short8v b1 = *(short8v*)(Wm1p + ((size_t)((ni*2+1)*64 + lane))*8);
    int chnk = ni*2 + (l15>>3);
    int cb = l15 & 7;
    #pragma unroll
    for (int mi=0;mi<4;++mi){
      f32x4 acc = {0.f,0.f,0.f,0.f};
      acc = __builtin_amdgcn_mfma_f32_16x16x32_bf16(a[mi*2+0], b0, acc, 0,0,0);
      acc = __builtin_amdgcn_mfma_f32_16x16x32_bf16(a[mi*2+1], b1, acc, 0,0,0);
      #pragma unroll
      for (int reg=0;reg<4;++reg){
        int row = mi*16 + g*4 + reg;
        Lh[((size_t)(chnk*64 + row))*8 + cb] = f2bf(siluf(acc[reg]*0.125f));
      }
    }
  }

  short8v a2[8];
  #pragma unroll
  for (int mi=0;mi<4;++mi){
    #pragma unroll
    for (int ks=0;ks<2;++ks)
      a2[mi*2+ks] = *(short8v*)(Lh + ((size_t)((ks*4+g)*64 + mi*16 + l15))*8);
  }
  f32x4 scv[4];
  #pragma unroll
  for (int mi=0;mi<4;++mi)
    scv[mi] = *(f32x4*)(&lds_s[wid][mi*16 + g*4]);

  #pragma unroll 1
  for (int ni=0;ni<11;++ni){
    short8v b0 = *(short8v*)(Wm2p + ((size_t)((ni*2+0)*64 + lane))*8);
    short8v b1 = *(short8v*)(Wm2p + ((size_t)((ni*2+1)*64 + lane))*8);
    #pragma unroll
    for (int mi=0;mi<4;++mi){
      f32x4 acc = {0.f,0.f,0.f,0.f};
      acc = __builtin_amdgcn_mfma_f32_16x16x32_bf16(a2[mi*2+0], b0, acc, 0,0,0);
      acc = __builtin_amdgcn_mfma_f32_16x16x32_bf16(a2[mi*2+1], b1, acc, 0,0,0);
      #pragma unroll
      for (int reg=0;reg<4;++reg){
        int row = mi*16 + g*4 + reg;
        int sl = wb + row;
        if (sl < nE)
          mixb[((size_t)ni*plane_stride + sl)*16 + l15] = f2bf(acc[reg]*scv[mi][reg]);
      }
    }
  }
}

// ---------------------------------------------------------------------------
// Edge-parallel tensor product with compile-time CG sparsity pruning.
// ---------------------------------------------------------------------------
template<int PIDX,int L1,int L2,int L3>
__device__ __forceinline__ void do_p(
    const float* __restrict__ cgtab, uint2 um,
    const float (&y1)[3], const float (&y2)[5],
    const float (&x0)[4], const float (&x1)[3][4], const float (&x2)[5][4],
    float (&msg0)[4], float (&msg1)[4][3], float (&msg2)[4][5])
{
  constexpr int d1=2*L1+1, d2=2*L2+1, d3=2*L3+1;
  const float* cgp = cgtab + PIDX*125;

  float yv[d2];
  if constexpr (L2==0){ yv[0]=1.0f; }
  else if constexpr (L2==1){ yv[0]=y1[0]; yv[1]=y1[1]; yv[2]=y1[2]; }
  else {
    #pragma unroll
    for (int j=0;j<5;++j) yv[j]=y2[j];
  }

  float M[d1][d3];
  #pragma unroll
  for (int iu=0;iu<d1;++iu){
    #pragma unroll
    for (int k=0;k<d3;++k){
      if (m_nz(L1,L2,L3,iu,k)){
        float acc = 0.f;
        #pragma unroll
        for (int j=0;j<d2;++j)
          if (cg_nz(L1,L2,L3,iu,j,k)) acc += yv[j]*cgp[(iu*5+j)*5+k];
        M[iu][k]=acc;
      } else {
        M[iu][k]=0.f;
      }
    }
  }

  float mx[4];
  mx[0] = __uint_as_float(um.x << 16);
  mx[1] = __uint_as_float(um.x & 0xffff0000u);
  mx[2] = __uint_as_float(um.y << 16);
  mx[3] = __uint_as_float(um.y & 0xffff0000u);

  #pragma unroll
  for (int c=0;c<4;++c){
    #pragma unroll
    for (int k=0;k<d3;++k){
      float t = 0.f;
      #pragma unroll
      for (int iu=0;iu<d1;++iu){
        if (m_nz(L1,L2,L3,iu,k)){
          float xv = (L1==0)? x0[c] : (L1==1? x1[iu][c] : x2[iu][c]);
          t += xv*M[iu][k];
        }
      }
      if constexpr (L3==0)      msg0[c]    += mx[c]*t;
      else if constexpr (L3==1) msg1[c][k] += mx[c]*t;
      else                      msg2[c][k] += mx[c]*t;
    }
  }
}

__global__ __launch_bounds__(256) void tp_kernel(
    const int* __restrict__ offsets,
    const int* __restrict__ nb,
    const unsigned short* __restrict__ mtabh,
    const float* __restrict__ cgtab,
    const unsigned short* __restrict__ mixb,
    const unsigned short* __restrict__ ylm,
    const int* __restrict__ sedge,
    int ci, int plane_stride,
    unsigned short* __restrict__ msgb)
{
  int t = blockIdx.x*256 + threadIdx.x;
  int slot = t >> 2;
  int sbase = offsets[nb[ci]];
  int nE = offsets[nb[ci+1]] - sbase;
  if (slot >= nE) return;
  int c0 = (t & 3)*4;

  union { uint4 u; unsigned short s[8]; } yv;
  yv.u = *(const uint4*)(ylm + (size_t)slot*8);
  int snd = sedge[slot];
  const unsigned short* xp = mtabh + (size_t)snd*144;

  float x0[4];
  float x1[3][4];
  float x2[5][4];
  unp4(*(const uint2*)(xp + c0), x0);
  #pragma unroll
  for (int iu=0;iu<3;++iu) unp4(*(const uint2*)(xp + 16 + iu*16 + c0), x1[iu]);
  #pragma unroll
  for (int iu=0;iu<5;++iu) unp4(*(const uint2*)(xp + 64 + iu*16 + c0), x2[iu]);

  float y1[3], y2[5];
  y1[0]=bf2f(yv.s[0]); y1[1]=bf2f(yv.s[1]); y1[2]=bf2f(yv.s[2]);
  y2[0]=bf2f(yv.s[3]); y2[1]=bf2f(yv.s[4]); y2[2]=bf2f(yv.s[5]);
  y2[3]=bf2f(yv.s[6]); y2[4]=bf2f(yv.s[7]);

  float msg0[4];
  float msg1[4][3];
  float msg2[4][5];
  #pragma unroll
  for (int c=0;c<4;++c){
    msg0[c]=0.f;
    #pragma unroll
    for (int i=0;i<3;++i) msg1[c][i]=0.f;
    #pragma unroll
    for (int i=0;i<5;++i) msg2[c][i]=0.f;
  }

  unsigned short* mr = msgb + (size_t)slot*144;
  #define UM(P) (*(const uint2*)(mixb + ((size_t)(P)*plane_stride + slot)*16 + c0))

  // ---- L3 = 0 group ----
  do_p< 0,0,0,0>(cgtab,UM(0),y1,y2,x0,x1,x2,msg0,msg1,msg2);
  do_p< 1,1,1,0>(cgtab,UM(1),y1,y2,x0,x1,x2,msg0,msg1,msg2);
  do_p< 2,2,2,0>(cgtab,UM(2),y1,y2,x0,x1,x2,msg0,msg1,msg2);
  {
    uint2 w;
    w.x = pk2(msg0[0], msg0[1]);
    w.y = pk2(msg0[2], msg0[3]);
    *(uint2*)(mr + c0) = w;
  }

  // ---- L3 = 1 group ----
  do_p< 3,0,1,1>(cgtab,UM(3),y1,y2,x0,x1,x2,msg0,msg1,msg2);
  do_p< 4,1,0,1>(cgtab,UM(4),y1,y2,x0,x1,x2,msg0,msg1,msg2);
  do_p< 5,1,2,1>(cgtab,UM(5),y1,y2,x0,x1,x2,msg0,msg1,msg2);
  do_p< 6,2,1,1>(cgtab,UM(6),y1,y2,x0,x1,x2,msg0,msg1,msg2);
  {
    unsigned short* p = mr + 16 + c0*3;
    uint2 w0, w1, w2;
    w0.x = pk2(msg1[0][0], msg1[0][1]);
    w0.y = pk2(msg1[0][2], msg1[1][0]);
    w1.x = pk2(msg1[1][1], msg1[1][2]);
    w1.y = pk2(msg1[2][0], msg1[2][1]);
    w2.x = pk2(msg1[2][2], msg1[3][0]);
    w2.y = pk2(msg1[3][1], msg1[3][2]);
    *(uint2*)(p) = w0;
    *(uint2*)(p+4) = w1;
    *(uint2*)(p+8) = w2;
  }

  // ---- L3 = 2 group ----
  do_p< 7,0,2,2>(cgtab,UM(7),y1,y2,x0,x1,x2,msg0,msg1,msg2);
  do_p< 8,1,1,2>(cgtab,UM(8),y1,y2,x0,x1,x2,msg0,msg1,msg2);
  do_p< 9,2,0,2>(cgtab,UM(9),y1,y2,x0,x1,x2,msg0,msg1,msg2);
  do_p<10,2,2,2>(cgtab,UM(10),y1,y2,x0,x1,x2,msg0,msg1,msg2);
  {
    unsigned short* p = mr + 64 + c0*5;
    #pragma unroll
    for (int w=0; w<5; ++w){
      int i0 = w*4;
      float v0 = msg2[(i0+0)/5][(i0+0)%5];
      float v1 = msg2[(i0+1)/5][(i0+1)%5];
      float v2 = msg2[(i0+2)/5][(i0+2)%5];
      float v3 = msg2[(i0+3)/5][(i0+3)%5];
      uint2 ww;
      ww.x = pk2(v0, v1);
      ww.y = pk2(v2, v3);
      *(uint2*)(p + i0) = ww;
    }
  }
  #undef UM
}

// ---------------------------------------------------------------------------
// Fused segmented-sum + node update. Block = 16 nodes x 16 threads.
// ---------------------------------------------------------------------------
__global__ __launch_bounds__(256) void seg_out_kernel(
    const int* __restrict__ offsets,
    const int* __restrict__ nb,
    const unsigned short* __restrict__ msgb,
    const float* __restrict__ nf,
    const int* __restrict__ species,
    const float* __restrict__ Wd0,
    const float* __restrict__ Wd1,
    const float* __restrict__ Wd2,
    const float* __restrict__ Wsk0,
    const float* __restrict__ Wsk1,
    const float* __restrict__ Wsk2,
    int ci,
    float* __restrict__ out)
{
  __shared__ float accum[16*144];

  int nlo = nb[ci], nhi = nb[ci+1];
  int nblk = blockIdx.x*16;
  if (nblk + 16 <= nlo || nblk >= nhi) return;

  int tid = threadIdx.x;
  int nloc = tid >> 4;
  int o = tid & 15;
  int n = nblk + nloc;
  bool active = (n >= nlo && n < nhi);

  int cbase = offsets[nlo];
  float acc[9];
  #pragma unroll
  for (int k=0;k<9;++k) acc[k]=0.f;
  if (active){
    int j0 = offsets[n] - cbase;
    int j1 = offsets[n+1] - cbase;
    for (int j=j0; j<j1; ++j){
      const unsigned short* mr = msgb + (size_t)j*144 + o*9;
      #pragma unroll
      for (int k=0;k<9;++k) acc[k] += bf2f(mr[k]);
    }
  }
  #pragma unroll
  for (int k=0;k<9;++k) accum[nloc*144 + o*9 + k] = acc[k];
  __syncthreads();
  if (!active) return;

  const float* an = accum + nloc*144;
  const float* f  = nf + (size_t)n*144;
  int sp = species[n];
  const float* wk0 = Wsk0 + sp*768;
  const float* wk1 = Wsk1 + sp*256;
  const float* wk2 = Wsk2 + sp*256;

  float sa0=0,sa1=0,sa2=0, sf0=0,sf1=0,sf2=0;
  #pragma unroll
  for (int c=0;c<16;++c){
    float aa = an[c], ff = f[c];
    sa0 += aa*Wd0[c*48+o];
    sa1 += aa*Wd0[c*48+16+o];
    sa2 += aa*Wd0[c*48+32+o];
    sf0 += ff*wk0[c*48+o];
    sf1 += ff*wk0[c*48+16+o];
    sf2 += ff*wk0[c*48+32+o];
  }
  float s0 = 0.0625f*sa0 + 0.25f*sf0;
  float s1 = 0.0625f*sa1 + 0.25f*sf1;
  float s2 = 0.0625f*sa2 + 0.25f*sf2;
  float scvv = siluf(s0);
  float g1  = siluf(s1);
  float g2  = siluf(s2);

  float v[3];
  #pragma unroll
  for (int i=0;i<3;++i){
    float av=0, fv=0;
    #pragma unroll
    for (int c=0;c<16;++c){
      av += an[16+c*3+i]*Wd1[c*16+o];
      fv += f[16+c*3+i]*wk1[c*16+o];
    }
    v[i] = (0.0625f*av + 0.25f*fv)*g1;
  }
  float q[5];
  #pragma unroll
  for (int i=0;i<5;++i){
    float av=0, fv=0;
    #pragma unroll
    for (int c=0;c<16;++c){
      av += an[64+c*5+i]*Wd2[c*16+o];
      fv += f[64+c*5+i]*wk2[c*16+o];
    }
    q[i] = (0.0625f*av + 0.25f*fv)*g2;
  }

  float* on = out + (size_t)n*144;
  on[o] = scvv;
  #pragma unroll
  for (int i=0;i<3;++i) on[16+o*3+i] = v[i];
  #pragma unroll
  for (int i=0;i<5;++i) on[64+o*5+i] = q[i];
}

// ---------------------------------------------------------------------------
extern "C" void kernel_launch(void* const* d_in, const int* in_sizes, int n_in,
                              void* d_out, int out_size, void* d_ws, size_t ws_size,
                              hipStream_t stream)
{
  const float* vectors    = (const float*)d_in[0];
  const float* node_feats = (const float*)d_in[1];
  const int*   species    = (const int*)d_in[2];
  const int*   senders    = (const int*)d_in[3];
  const int*   receivers  = (const int*)d_in[4];
  const float* W_up0 = (const float*)d_in[5];
  const float* W_up1 = (const float*)d_in[6];
  const float* W_up2 = (const float*)d_in[7];
  const float* Wm0   = (const float*)d_in[8];
  const float* Wm1   = (const float*)d_in[9];
  const float* Wm2   = (const float*)d_in[10];
  const float* Wd0   = (const float*)d_in[11];
  const float* Wd1   = (const float*)d_in[12];
  const float* Wd2   = (const float*)d_in[13];
  const float* Wsk0  = (const float*)d_in[14];
  const float* Wsk1  = (const float*)d_in[15];
  const float* Wsk2  = (const float*)d_in[16];
  float* out = (float*)d_out;
  float* ws  = (float*)d_ws;

  float* cgbuf = ws;
  unsigned short* mtabh = (unsigned short*)(ws + 2048);
  int* counts      = (int*)(ws + 2048 + (size_t)NN*72);
  int* cursor      = counts + NN;
  int* offsets     = cursor + NN;
  int* edge_sorted = offsets + NN + 64;
  int* nb          = edge_sorted + NE;
  unsigned short* Wm1p = (unsigned short*)(nb + 16);
  unsigned short* Wm2p = Wm1p + 4096;
  unsigned short* Wm0p = Wm2p + 11264;
  unsigned short* mixb = Wm0p + 2048;

  size_t fixed_f = 2048 + (size_t)NN*72 + NN + NN + (NN+64) + NE + 16 + 2048 + 5632 + 1024;
  size_t ws_f = ws_size/4;
  // per-edge ws: mixb 88f + ylm 4f + sedge 1f + msgb 72f = 165 f
  long long cap_rows = (ws_f > fixed_f) ? (long long)((ws_f - fixed_f)/165) : 0;
  long long capm = cap_rows - 8192;
  if (capm < 16384) capm = 16384;
  int NC = (int)((NE + capm - 1)/capm);
  if (NC < 1) NC = 1;
  if (NC > 15) NC = 15;
  int plane_stride = (int)(NE/NC + 4096);

  unsigned short* ylm  = mixb + (size_t)11*plane_stride*16;
  int* sedge           = (int*)(ylm + (size_t)plane_stride*8);
  unsigned short* msgb = (unsigned short*)(sedge + plane_stride);

  hipMemsetAsync(counts, 0, 2*(size_t)NN*sizeof(int), stream);
  init_kernel<<<79, 256, 0, stream>>>(Wm0, Wm1, Wm2, cgbuf, Wm0p, Wm1p, Wm2p);
  node_up_kernel<<<(NN*144)/256, 256, 0, stream>>>(node_feats, W_up0, W_up1, W_up2, mtabh);
  hist_kernel<<<NE/256, 256, 0, stream>>>(receivers, counts);
  scan_kernel<<<1, 1024, 0, stream>>>(counts, offsets, nb, NC);
  scatter_kernel<<<NE/256, 256, 0, stream>>>(receivers, offsets, cursor, edge_sorted);

  long long chunk_edges_max = NE/NC + 4096;
  int gA  = (int)((chunk_edges_max + 255)/256);
  int gTP = (int)((chunk_edges_max*4 + 255)/256);
  int gSO = (NN + 15)/16;
  for (int ci = 0; ci < NC; ++ci){
    edge_mix_kernel<<<gA, 256, 0, stream>>>(vectors, senders, edge_sorted,
                                            offsets, nb, Wm0p, Wm1p, Wm2p,
                                            ci, plane_stride, mixb, ylm, sedge);
    tp_kernel<<<gTP, 256, 0, stream>>>(offsets, nb, mtabh, cgbuf, mixb, ylm,
                                       sedge, ci, plane_stride, msgb);
    seg_out_kernel<<<gSO, 256, 0, stream>>>(offsets, nb, msgb, node_feats,
                                            species, Wd0, Wd1, Wd2,
                                            Wsk0, Wsk1, Wsk2, ci, out);
  }
}

// Round 14
// 355.992 us; speedup vs baseline: 1.0226x; 1.0226x over previous
//
#include <hip/hip_runtime.h>
#include <math.h>

#define NN 32768
#define NE 524288

typedef __attribute__((ext_vector_type(8))) short short8v;
typedef __attribute__((ext_vector_type(4))) float f32x4;

__device__ __forceinline__ float siluf(float x){
  return x * __builtin_amdgcn_rcpf(1.0f + __expf(-x));
}

__device__ __forceinline__ unsigned short f2bf(float x){
  unsigned int b = __float_as_uint(x);
  unsigned int r = ((b >> 16) & 1u) + 0x7fffu;
  return (unsigned short)((b + r) >> 16);
}

__device__ __forceinline__ unsigned int pk2(float a, float b){
  return (unsigned int)f2bf(a) | ((unsigned int)f2bf(b) << 16);
}

__device__ __forceinline__ float bf2f(unsigned short v){
  return __uint_as_float(((unsigned int)v) << 16);
}

__device__ __forceinline__ void unp2(unsigned int u, float* x){
  x[0] = __uint_as_float(u << 16);
  x[1] = __uint_as_float(u & 0xffff0000u);
}

// Real-basis CG structural-nonzero mask (superset-safe selection rules).
__device__ __host__ constexpr bool cg_nz(int l1,int l2,int l3,int i,int j,int k){
  int m1=i-l1, m2=j-l2, m3=k-l3;
  int a1=m1<0?-m1:m1, a2=m2<0?-m2:m2, a3=m3<0?-m3:m3;
  int neg=(m1<0?1:0)+(m2<0?1:0)+(m3<0?1:0);
  bool par=(neg&1)==0;
  bool mag=(a3==a1+a2)||(a3==a1-a2)||(a3==a2-a1);
  return par&&mag;
}
__device__ __host__ constexpr bool m_nz(int l1,int l2,int l3,int i,int k){
  for(int j=0;j<2*l2+1;++j) if(cg_nz(l1,l2,l3,i,j,k)) return true;
  return false;
}

__device__ const int d_PL1[11] = {0,1,2,0,1,1,2,0,1,2,2};
__device__ const int d_PL2[11] = {0,1,2,1,0,2,1,2,1,0,2};
__device__ const int d_PL3[11] = {0,0,0,1,1,1,1,2,2,2,2};

// ---------------------------------------------------------------------------
// CG math (1/PATH_NORM folded).
// ---------------------------------------------------------------------------
__device__ double factd(int n){ double r=1.0; for(int i=2;i<=n;++i) r*=(double)i; return r; }

__device__ double su2_elem(int l1,int l2,int l3,int m1,int m2){
  int m3=m1+m2;
  if (m3 < -l3 || m3 > l3) return 0.0;
  double pref = sqrt((double)(2*l3+1)*factd(l3+l1-l2)*factd(l3-l1+l2)*factd(l1+l2-l3)/factd(l1+l2+l3+1));
  pref *= sqrt(factd(l3+m3)*factd(l3-m3)*factd(l1-m1)*factd(l1+m1)*factd(l2-m2)*factd(l2+m2));
  double s=0.0;
  for (int k=0;k<=l1+l2-l3;++k){
    int t1=l1+l2-l3-k, t2=l1-m1-k, t3=l2+m2-k, t4=l3-l2+m1+k, t5=l3-l1-m2+k;
    if (t1<0||t2<0||t3<0||t4<0||t5<0) continue;
    double d = factd(k)*factd(t1)*factd(t2)*factd(t3)*factd(t4)*factd(t5);
    s += ((k&1)? -1.0:1.0)/d;
  }
  return pref*s;
}

__device__ void q_elem(int l,int a,int i,double& re,double& im){
  re=0.0; im=0.0;
  const double is2 = 0.7071067811865476;
  int m = a - l;
  if (m==0){ if (i==l) re=1.0; return; }
  if (m>0){
    if (i==l+m)      re = (m&1)? -is2: is2;
    else if (i==l-m) re = is2;
  } else {
    int mm=-m;
    if (i==l-mm)      im = is2;
    else if (i==l+mm) im = (mm&1)? is2 : -is2;
  }
}

// ---------------------------------------------------------------------------
// init kernel: blocks 0..10 = CG table; blocks 11..78 = weight packing.
// ---------------------------------------------------------------------------
__global__ void init_kernel(const float* __restrict__ Wm0,
                            const float* __restrict__ Wm1,
                            const float* __restrict__ Wm2,
                            float* __restrict__ cgout,
                            unsigned short* __restrict__ Wm0p,
                            unsigned short* __restrict__ Wm1p,
                            unsigned short* __restrict__ Wm2p)
{
  if (blockIdx.x < 11){
    int p = blockIdx.x;
    int t = threadIdx.x;
    if (t >= 125) return;
    int a = t/25, b = (t/5)%5, c = t%5;
    int l1=d_PL1[p], l2=d_PL2[p], l3=d_PL3[p];
    int n1=2*l1+1, n2=2*l2+1, n3=2*l3+1;
    float outv = 0.0f;
    if (a<n1 && b<n2 && c<n3){
      double acc = 0.0;
      for (int i=0;i<n1;++i)
        for (int j=0;j<n2;++j){
          int m1=i-l1, m2=j-l2;
          int m3=m1+m2;
          if (m3 < -l3 || m3 > l3) continue;
          double cv = su2_elem(l1,l2,l3,m1,m2);
          if (cv==0.0) continue;
          int k = m3 + l3;
          double a1r,a1i,a2r,a2i,a3r,a3i;
          q_elem(l1,a,i,a1r,a1i);
          q_elem(l2,b,j,a2r,a2i);
          q_elem(l3,c,k,a3r,a3i);
          double re = (a1r*a2r - a1i*a2i)*a3r + (a1r*a2i + a1i*a2r)*a3i;
          acc += cv*re;
        }
      double invn = (l3==0)? 0.5773502691896258 : 0.5;
      outv = (float)(acc*invn);
    }
    cgout[p*125 + (a*5+b)*5 + c] = outv;
  } else {
    int t = (blockIdx.x - 11)*256 + threadIdx.x;
    if (t < 4096){
      int j = t & 7, lane = (t>>3)&63, ks = (t>>9)&1, ni = t>>10;
      int k = ks*32 + (lane>>4)*8 + j;
      int col = ni*16 + (lane&15);
      Wm1p[t] = f2bf(Wm1[k*64+col]);
    }
    int t2 = t - 4096;
    if (t2 >= 0 && t2 < 11264){
      int j = t2 & 7, lane = (t2>>3)&63, ks = (t2>>9)&1, ni = t2>>10;
      int k = ks*32 + (lane>>4)*8 + j;
      int col = ni*16 + (lane&15);
      Wm2p[t2] = f2bf(Wm2[k*176+col]);
    }
    int t3 = t - 15360;
    if (t3 >= 0 && t3 < 2048){
      int j = t3 & 7, lane = (t3>>3)&63, ni = t3>>9;
      int k = (lane>>4)*8 + j;
      int col = ni*16 + (lane&15);
      Wm0p[t3] = (k < 8) ? f2bf(Wm0[k*64+col]*0.3535533906f) : (unsigned short)0;
    }
  }
}

// ---------------------------------------------------------------------------
// Node up-projection -> bf16, iu-major layout (scaled 0.25).
// ---------------------------------------------------------------------------
__global__ __launch_bounds__(256) void node_up_kernel(
    const float* __restrict__ nf,
    const float* __restrict__ W0,
    const float* __restrict__ W1,
    const float* __restrict__ W2,
    unsigned short* __restrict__ mtabh)
{
  int gidx = blockIdx.x*256 + threadIdx.x;
  if (gidx >= NN*144) return;
  int n = gidx/144;
  int col = gidx - n*144;
  const float* f = nf + (size_t)n*144;
  float acc = 0.f;
  if (col < 16){
    int o = col;
    #pragma unroll
    for (int c=0;c<16;++c) acc += f[c]*W0[c*16+o];
  } else if (col < 64){
    int idx = col-16;
    int iu = idx >> 4, o = idx & 15;
    #pragma unroll
    for (int c=0;c<16;++c) acc += f[16+c*3+iu]*W1[c*16+o];
  } else {
    int idx = col-64;
    int iu = idx >> 4, o = idx & 15;
    #pragma unroll
    for (int c=0;c<16;++c) acc += f[64+c*5+iu]*W2[c*16+o];
  }
  mtabh[gidx] = f2bf(0.25f*acc);
}

// ---------------------------------------------------------------------------
// CSR build
// ---------------------------------------------------------------------------
__global__ __launch_bounds__(256) void hist_kernel(
    const int* __restrict__ recv, int* __restrict__ counts)
{
  int e = blockIdx.x*256 + threadIdx.x;
  if (e < NE) atomicAdd(&counts[recv[e]], 1);
}

__global__ __launch_bounds__(1024) void scan_kernel(
    const int* __restrict__ counts, int* __restrict__ offsets,
    int* __restrict__ nb, int NC)
{
  __shared__ int part[1024];
  int t = threadIdx.x;
  int local[32];
  int s = 0;
  #pragma unroll
  for (int i=0;i<32;++i){ local[i]=counts[t*32+i]; s+=local[i]; }
  part[t]=s;
  __syncthreads();
  for (int off=1; off<1024; off<<=1){
    int v = (t>=off)? part[t-off] : 0;
    __syncthreads();
    part[t] += v;
    __syncthreads();
  }
  int base = part[t] - s;
  int run = base;
  #pragma unroll
  for (int i=0;i<32;++i){ offsets[t*32+i]=run; run+=local[i]; }
  if (t==1023) offsets[NN]=run;

  for (int i=1; i<NC; ++i){
    long long Ti = (long long)NE*i/NC;
    if ((long long)base <= Ti && Ti < (long long)part[t]){
      int run2 = base;
      #pragma unroll
      for (int k=0;k<32;++k){
        int nxt = run2 + local[k];
        if (run2 <= Ti && Ti < nxt) nb[i] = t*32 + k + 1;
        run2 = nxt;
      }
    }
  }
  if (t==0) nb[0]=0;
  if (t==1023) nb[NC]=NN;
}

__global__ __launch_bounds__(256) void scatter_kernel(
    const int* __restrict__ recv, const int* __restrict__ offsets,
    int* __restrict__ cursor, int* __restrict__ edge_sorted)
{
  int e = blockIdx.x*256 + threadIdx.x;
  if (e < NE){
    int r = recv[e];
    int pos = atomicAdd(&cursor[r], 1);
    edge_sorted[offsets[r] + pos] = e;
  }
}

// ---------------------------------------------------------------------------
// Edge MLP + mix, all GEMMs on MFMA. One wave per block (LDS 8.4 KB).
// ---------------------------------------------------------------------------
__global__ __launch_bounds__(64) void edge_mix_kernel(
    const float* __restrict__ vectors,
    const int* __restrict__ senders,
    const int* __restrict__ edge_sorted,
    const int* __restrict__ offsets,
    const int* __restrict__ nb,
    const unsigned short* __restrict__ Wm0p,
    const unsigned short* __restrict__ Wm1p,
    const unsigned short* __restrict__ Wm2p,
    int ci, int plane_stride,
    unsigned short* __restrict__ mixb,
    unsigned short* __restrict__ ylm,
    int* __restrict__ sedge)
{
  __shared__ unsigned short lds_h[8*64*8];
  __shared__ float lds_s[64];

  int sbase = offsets[nb[ci]];
  int nE = offsets[nb[ci+1]] - sbase;
  int lane = threadIdx.x;
  int g = lane >> 4;
  int l15 = lane & 15;
  int wb = blockIdx.x*64;
  int slot = wb + lane;

  float vx=0.f, vy=0.f, vz=0.f;
  int snd = 0;
  if (slot < nE){
    int e = edge_sorted[sbase + slot];
    vx = vectors[(size_t)e*3+0];
    vy = vectors[(size_t)e*3+1];
    vz = vectors[(size_t)e*3+2];
    snd = senders[e];
  }
  float r = sqrtf(vx*vx + vy*vy + vz*vz);
  float safe = (r > 1e-9f) ? r : 1.0f;
  float inv_safe = 1.0f/safe;

  const float PIf = 3.14159265358979f;
  float xc = fminf(r*0.25f, 1.0f);
  float s1 = __sinf(PIf*xc);
  float c1 = __cosf(PIf*xc);
  float env = 0.5f*(c1 + 1.0f);
  float pref = 0.70710678118f * env * inv_safe;
  float rb[8];
  {
    float sk=s1, ck=c1;
    rb[0]=pref*sk;
    #pragma unroll
    for (int k=1;k<8;++k){
      float sn = sk*c1 + ck*s1;
      float cn = ck*c1 - sk*s1;
      sk=sn; ck=cn;
      rb[k]=pref*sk;
    }
  }

  if (slot < nE){
    float ux=vx*inv_safe, uy=vy*inv_safe, uz=vz*inv_safe;
    const float SQ3  = 1.73205080757f;
    const float SQ15 = 3.87298334621f;
    union { uint4 u; unsigned short s[8]; } yv;
    yv.s[0]=f2bf(SQ3*uy);  yv.s[1]=f2bf(SQ3*uz);  yv.s[2]=f2bf(SQ3*ux);
    yv.s[3]=f2bf(SQ15*ux*uy);
    yv.s[4]=f2bf(SQ15*uy*uz);
    yv.s[5]=f2bf(1.11803398875f*(3.f*uz*uz-1.f));
    yv.s[6]=f2bf(SQ15*ux*uz);
    yv.s[7]=f2bf(1.93649167310f*(ux*ux-uy*uy));
    *(uint4*)(ylm + (size_t)slot*8) = yv.u;
    sedge[slot] = snd;
  }

  unsigned short* Lh = lds_h;

  {
    union { uint4 u; unsigned short s[8]; } rv;
    #pragma unroll
    for (int k=0;k<8;++k) rv.s[k]=f2bf(rb[k]);
    *(uint4*)(Lh + (size_t)lane*8) = rv.u;
  }
  lds_s[lane] = (r == 0.0f) ? 0.0f : 0.125f;

  __syncthreads();

  // ---- layer 1 via MFMA ----
  short8v a1[4];
  {
    short8v zz = {0,0,0,0,0,0,0,0};
    #pragma unroll
    for (int mi=0;mi<4;++mi){
      short8v av = *(short8v*)(Lh + (size_t)(mi*16 + l15)*8);
      a1[mi] = (g==0) ? av : zz;
    }
  }
  #pragma unroll
  for (int ni=0;ni<4;++ni){
    short8v b = *(short8v*)(Wm0p + ((size_t)(ni*64 + lane))*8);
    #pragma unroll
    for (int mi=0;mi<4;++mi){
      f32x4 acc = {0.f,0.f,0.f,0.f};
      acc = __builtin_amdgcn_mfma_f32_16x16x32_bf16(a1[mi], b, acc, 0,0,0);
      int col = ni*16 + l15;
      int c = col >> 3, cb = col & 7;
      #pragma unroll
      for (int reg=0;reg<4;++reg){
        int row = mi*16 + g*4 + reg;
        Lh[((size_t)(c*64 + row))*8 + cb] = f2bf(siluf(acc[reg]));
      }
    }
  }

  __syncthreads();

  // ---- layer 2 via MFMA ----
  short8v a[8];
  #pragma unroll
  for (int mi=0;mi<4;++mi){
    #pragma unroll
    for (int ks=0;ks<2;++ks)
      a[mi*2+ks] = *(short8v*)(Lh + ((size_t)((ks*4+g)*64 + mi*16 + l15))*8);
  }
  #pragma unroll 1
  for (int ni=0;ni<4;++ni){
    short8v b0 = *(short8v*)(Wm1p + ((size_t)((ni*2+0)*64 + lane))*8);
    short8v b1 = *(short8v*)(Wm1p + ((size_t)((ni*2+1)*64 + lane))*8);
    int chnk = ni*2 + (l15>>3);
    int cb = l15 & 7;
    #pragma unroll
    for (int mi=0;mi<4;++mi){
      f32x4 acc = {0.f,0.f,0.f,0.f};
      acc = __builtin_amdgcn_mfma_f32_16x16x32_bf16(a[mi*2+0], b0, acc, 0,0,0);
      acc = __builtin_amdgcn_mfma_f32_16x16x32_bf16(a[mi*2+1], b1, acc, 0,0,0);
      #pragma unroll
      for (int reg=0;reg<4;++reg){
        int row = mi*16 + g*4 + reg;
        Lh[((size_t)(chnk*64 + row))*8 + cb] = f2bf(siluf(acc[reg]*0.125f));
      }
    }
  }

  short8v a2[8];
  #pragma unroll
  for (int mi=0;mi<4;++mi){
    #pragma unroll
    for (int ks=0;ks<2;++ks)
      a2[mi*2+ks] = *(short8v*)(Lh + ((size_t)((ks*4+g)*64 + mi*16 + l15))*8);
  }
  f32x4 scv[4];
  #pragma unroll
  for (int mi=0;mi<4;++mi)
    scv[mi] = *(f32x4*)(&lds_s[mi*16 + g*4]);

  #pragma unroll 1
  for (int ni=0;ni<11;++ni){
    short8v b0 = *(short8v*)(Wm2p + ((size_t)((ni*2+0)*64 + lane))*8);
    short8v b1 = *(short8v*)(Wm2p + ((size_t)((ni*2+1)*64 + lane))*8);
    #pragma unroll
    for (int mi=0;mi<4;++mi){
      f32x4 acc = {0.f,0.f,0.f,0.f};
      acc = __builtin_amdgcn_mfma_f32_16x16x32_bf16(a2[mi*2+0], b0, acc, 0,0,0);
      acc = __builtin_amdgcn_mfma_f32_16x16x32_bf16(a2[mi*2+1], b1, acc, 0,0,0);
      #pragma unroll
      for (int reg=0;reg<4;++reg){
        int row = mi*16 + g*4 + reg;
        int sl = wb + row;
        if (sl < nE)
          mixb[((size_t)ni*plane_stride + sl)*16 + l15] = f2bf(acc[reg]*scv[mi][reg]);
      }
    }
  }
}

// ---------------------------------------------------------------------------
// Edge-parallel tensor product, 2 channels/thread (8 threads/slot) for max
// wave parallelism; compile-time CG sparsity pruning.
// ---------------------------------------------------------------------------
template<int PIDX,int L1,int L2,int L3>
__device__ __forceinline__ void do_p(
    const float* __restrict__ cgtab, unsigned int um,
    const float (&y1)[3], const float (&y2)[5],
    const float (&x0)[2], const float (&x1)[3][2], const float (&x2)[5][2],
    float (&msg0)[2], float (&msg1)[2][3], float (&msg2)[2][5])
{
  constexpr int d1=2*L1+1, d2=2*L2+1, d3=2*L3+1;
  const float* cgp = cgtab + PIDX*125;

  float yv[d2];
  if constexpr (L2==0){ yv[0]=1.0f; }
  else if constexpr (L2==1){ yv[0]=y1[0]; yv[1]=y1[1]; yv[2]=y1[2]; }
  else {
    #pragma unroll
    for (int j=0;j<5;++j) yv[j]=y2[j];
  }

  float M[d1][d3];
  #pragma unroll
  for (int iu=0;iu<d1;++iu){
    #pragma unroll
    for (int k=0;k<d3;++k){
      if (m_nz(L1,L2,L3,iu,k)){
        float acc = 0.f;
        #pragma unroll
        for (int j=0;j<d2;++j)
          if (cg_nz(L1,L2,L3,iu,j,k)) acc += yv[j]*cgp[(iu*5+j)*5+k];
        M[iu][k]=acc;
      } else {
        M[iu][k]=0.f;
      }
    }
  }

  float mx[2];
  mx[0] = __uint_as_float(um << 16);
  mx[1] = __uint_as_float(um & 0xffff0000u);

  #pragma unroll
  for (int c=0;c<2;++c){
    #pragma unroll
    for (int k=0;k<d3;++k){
      float t = 0.f;
      #pragma unroll
      for (int iu=0;iu<d1;++iu){
        if (m_nz(L1,L2,L3,iu,k)){
          float xv = (L1==0)? x0[c] : (L1==1? x1[iu][c] : x2[iu][c]);
          t += xv*M[iu][k];
        }
      }
      if constexpr (L3==0)      msg0[c]    += mx[c]*t;
      else if constexpr (L3==1) msg1[c][k] += mx[c]*t;
      else                      msg2[c][k] += mx[c]*t;
    }
  }
}

__global__ __launch_bounds__(256) void tp_kernel(
    const int* __restrict__ offsets,
    const int* __restrict__ nb,
    const unsigned short* __restrict__ mtabh,
    const float* __restrict__ cgtab,
    const unsigned short* __restrict__ mixb,
    const unsigned short* __restrict__ ylm,
    const int* __restrict__ sedge,
    int ci, int plane_stride,
    unsigned short* __restrict__ msgb)
{
  int t = blockIdx.x*256 + threadIdx.x;
  int slot = t >> 3;
  int sbase = offsets[nb[ci]];
  int nE = offsets[nb[ci+1]] - sbase;
  if (slot >= nE) return;
  int c0 = (t & 7)*2;

  union { uint4 u; unsigned short s[8]; } yv;
  yv.u = *(const uint4*)(ylm + (size_t)slot*8);
  int snd = sedge[slot];
  const unsigned short* xp = mtabh + (size_t)snd*144;

  float x0[2];
  float x1[3][2];
  float x2[5][2];
  unp2(*(const unsigned int*)(xp + c0), x0);
  #pragma unroll
  for (int iu=0;iu<3;++iu) unp2(*(const unsigned int*)(xp + 16 + iu*16 + c0), x1[iu]);
  #pragma unroll
  for (int iu=0;iu<5;++iu) unp2(*(const unsigned int*)(xp + 64 + iu*16 + c0), x2[iu]);

  float y1[3], y2[5];
  y1[0]=bf2f(yv.s[0]); y1[1]=bf2f(yv.s[1]); y1[2]=bf2f(yv.s[2]);
  y2[0]=bf2f(yv.s[3]); y2[1]=bf2f(yv.s[4]); y2[2]=bf2f(yv.s[5]);
  y2[3]=bf2f(yv.s[6]); y2[4]=bf2f(yv.s[7]);

  float msg0[2];
  float msg1[2][3];
  float msg2[2][5];
  #pragma unroll
  for (int c=0;c<2;++c){
    msg0[c]=0.f;
    #pragma unroll
    for (int i=0;i<3;++i) msg1[c][i]=0.f;
    #pragma unroll
    for (int i=0;i<5;++i) msg2[c][i]=0.f;
  }

  unsigned short* mr = msgb + (size_t)slot*144;
  #define UM(P) (*(const unsigned int*)(mixb + ((size_t)(P)*plane_stride + slot)*16 + c0))

  // ---- L3 = 0 group ----
  do_p< 0,0,0,0>(cgtab,UM(0),y1,y2,x0,x1,x2,msg0,msg1,msg2);
  do_p< 1,1,1,0>(cgtab,UM(1),y1,y2,x0,x1,x2,msg0,msg1,msg2);
  do_p< 2,2,2,0>(cgtab,UM(2),y1,y2,x0,x1,x2,msg0,msg1,msg2);
  *(unsigned int*)(mr + c0) = pk2(msg0[0], msg0[1]);

  // ---- L3 = 1 group ----
  do_p< 3,0,1,1>(cgtab,UM(3),y1,y2,x0,x1,x2,msg0,msg1,msg2);
  do_p< 4,1,0,1>(cgtab,UM(4),y1,y2,x0,x1,x2,msg0,msg1,msg2);
  do_p< 5,1,2,1>(cgtab,UM(5),y1,y2,x0,x1,x2,msg0,msg1,msg2);
  do_p< 6,2,1,1>(cgtab,UM(6),y1,y2,x0,x1,x2,msg0,msg1,msg2);
  {
    unsigned short* p = mr + 16 + c0*3;
    *(unsigned int*)(p)   = pk2(msg1[0][0], msg1[0][1]);
    *(unsigned int*)(p+2) = pk2(msg1[0][2], msg1[1][0]);
    *(unsigned int*)(p+4) = pk2(msg1[1][1], msg1[1][2]);
  }

  // ---- L3 = 2 group ----
  do_p< 7,0,2,2>(cgtab,UM(7),y1,y2,x0,x1,x2,msg0,msg1,msg2);
  do_p< 8,1,1,2>(cgtab,UM(8),y1,y2,x0,x1,x2,msg0,msg1,msg2);
  do_p< 9,2,0,2>(cgtab,UM(9),y1,y2,x0,x1,x2,msg0,msg1,msg2);
  do_p<10,2,2,2>(cgtab,UM(10),y1,y2,x0,x1,x2,msg0,msg1,msg2);
  {
    unsigned short* p = mr + 64 + c0*5;
    *(unsigned int*)(p)   = pk2(msg2[0][0], msg2[0][1]);
    *(unsigned int*)(p+2) = pk2(msg2[0][2], msg2[0][3]);
    *(unsigned int*)(p+4) = pk2(msg2[0][4], msg2[1][0]);
    *(unsigned int*)(p+6) = pk2(msg2[1][1], msg2[1][2]);
    *(unsigned int*)(p+8) = pk2(msg2[1][3], msg2[1][4]);
  }
  #undef UM
}

// ---------------------------------------------------------------------------
// Fused segmented-sum + node update. Block = 16 nodes x 16 threads.
// ---------------------------------------------------------------------------
__global__ __launch_bounds__(256) void seg_out_kernel(
    const int* __restrict__ offsets,
    const int* __restrict__ nb,
    const unsigned short* __restrict__ msgb,
    const float* __restrict__ nf,
    const int* __restrict__ species,
    const float* __restrict__ Wd0,
    const float* __restrict__ Wd1,
    const float* __restrict__ Wd2,
    const float* __restrict__ Wsk0,
    const float* __restrict__ Wsk1,
    const float* __restrict__ Wsk2,
    int ci,
    float* __restrict__ out)
{
  __shared__ float accum[16*144];

  int nlo = nb[ci], nhi = nb[ci+1];
  int nblk = blockIdx.x*16;
  if (nblk + 16 <= nlo || nblk >= nhi) return;

  int tid = threadIdx.x;
  int nloc = tid >> 4;
  int o = tid & 15;
  int n = nblk + nloc;
  bool active = (n >= nlo && n < nhi);

  int cbase = offsets[nlo];
  float acc[9];
  #pragma unroll
  for (int k=0;k<9;++k) acc[k]=0.f;
  if (active){
    int j0 = offsets[n] - cbase;
    int j1 = offsets[n+1] - cbase;
    for (int j=j0; j<j1; ++j){
      const unsigned short* mr = msgb + (size_t)j*144 + o*9;
      #pragma unroll
      for (int k=0;k<9;++k) acc[k] += bf2f(mr[k]);
    }
  }
  #pragma unroll
  for (int k=0;k<9;++k) accum[nloc*144 + o*9 + k] = acc[k];
  __syncthreads();
  if (!active) return;

  const float* an = accum + nloc*144;
  const float* f  = nf + (size_t)n*144;
  int sp = species[n];
  const float* wk0 = Wsk0 + sp*768;
  const float* wk1 = Wsk1 + sp*256;
  const float* wk2 = Wsk2 + sp*256;

  float sa0=0,sa1=0,sa2=0, sf0=0,sf1=0,sf2=0;
  #pragma unroll
  for (int c=0;c<16;++c){
    float aa = an[c], ff = f[c];
    sa0 += aa*Wd0[c*48+o];
    sa1 += aa*Wd0[c*48+16+o];
    sa2 += aa*Wd0[c*48+32+o];
    sf0 += ff*wk0[c*48+o];
    sf1 += ff*wk0[c*48+16+o];
    sf2 += ff*wk0[c*48+32+o];
  }
  float s0 = 0.0625f*sa0 + 0.25f*sf0;
  float s1 = 0.0625f*sa1 + 0.25f*sf1;
  float s2 = 0.0625f*sa2 + 0.25f*sf2;
  float scvv = siluf(s0);
  float g1  = siluf(s1);
  float g2  = siluf(s2);

  float v[3];
  #pragma unroll
  for (int i=0;i<3;++i){
    float av=0, fv=0;
    #pragma unroll
    for (int c=0;c<16;++c){
      av += an[16+c*3+i]*Wd1[c*16+o];
      fv += f[16+c*3+i]*wk1[c*16+o];
    }
    v[i] = (0.0625f*av + 0.25f*fv)*g1;
  }
  float q[5];
  #pragma unroll
  for (int i=0;i<5;++i){
    float av=0, fv=0;
    #pragma unroll
    for (int c=0;c<16;++c){
      av += an[64+c*5+i]*Wd2[c*16+o];
      fv += f[64+c*5+i]*wk2[c*16+o];
    }
    q[i] = (0.0625f*av + 0.25f*fv)*g2;
  }

  float* on = out + (size_t)n*144;
  on[o] = scvv;
  #pragma unroll
  for (int i=0;i<3;++i) on[16+o*3+i] = v[i];
  #pragma unroll
  for (int i=0;i<5;++i) on[64+o*5+i] = q[i];
}

// ---------------------------------------------------------------------------
extern "C" void kernel_launch(void* const* d_in, const int* in_sizes, int n_in,
                              void* d_out, int out_size, void* d_ws, size_t ws_size,
                              hipStream_t stream)
{
  const float* vectors    = (const float*)d_in[0];
  const float* node_feats = (const float*)d_in[1];
  const int*   species    = (const int*)d_in[2];
  const int*   senders    = (const int*)d_in[3];
  const int*   receivers  = (const int*)d_in[4];
  const float* W_up0 = (const float*)d_in[5];
  const float* W_up1 = (const float*)d_in[6];
  const float* W_up2 = (const float*)d_in[7];
  const float* Wm0   = (const float*)d_in[8];
  const float* Wm1   = (const float*)d_in[9];
  const float* Wm2   = (const float*)d_in[10];
  const float* Wd0   = (const float*)d_in[11];
  const float* Wd1   = (const float*)d_in[12];
  const float* Wd2   = (const float*)d_in[13];
  const float* Wsk0  = (const float*)d_in[14];
  const float* Wsk1  = (const float*)d_in[15];
  const float* Wsk2  = (const float*)d_in[16];
  float* out = (float*)d_out;
  float* ws  = (float*)d_ws;

  float* cgbuf = ws;
  unsigned short* mtabh = (unsigned short*)(ws + 2048);
  int* counts      = (int*)(ws + 2048 + (size_t)NN*72);
  int* cursor      = counts + NN;
  int* offsets     = cursor + NN;
  int* edge_sorted = offsets + NN + 64;
  int* nb          = edge_sorted + NE;
  unsigned short* Wm1p = (unsigned short*)(nb + 16);
  unsigned short* Wm2p = Wm1p + 4096;
  unsigned short* Wm0p = Wm2p + 11264;
  unsigned short* mixb = Wm0p + 2048;

  size_t fixed_f = 2048 + (size_t)NN*72 + NN + NN + (NN+64) + NE + 16 + 2048 + 5632 + 1024;
  size_t ws_f = ws_size/4;
  // per-edge ws: mixb 88f + ylm 4f + sedge 1f + msgb 72f = 165 f
  long long cap_rows = (ws_f > fixed_f) ? (long long)((ws_f - fixed_f)/165) : 0;
  long long capm = cap_rows - 8192;
  if (capm < 16384) capm = 16384;
  int NC = (int)((NE + capm - 1)/capm);
  if (NC < 1) NC = 1;
  if (NC > 15) NC = 15;
  int plane_stride = (int)(NE/NC + 4096);

  unsigned short* ylm  = mixb + (size_t)11*plane_stride*16;
  int* sedge           = (int*)(ylm + (size_t)plane_stride*8);
  unsigned short* msgb = (unsigned short*)(sedge + plane_stride);

  hipMemsetAsync(counts, 0, 2*(size_t)NN*sizeof(int), stream);
  init_kernel<<<79, 256, 0, stream>>>(Wm0, Wm1, Wm2, cgbuf, Wm0p, Wm1p, Wm2p);
  node_up_kernel<<<(NN*144)/256, 256, 0, stream>>>(node_feats, W_up0, W_up1, W_up2, mtabh);
  hist_kernel<<<NE/256, 256, 0, stream>>>(receivers, counts);
  scan_kernel<<<1, 1024, 0, stream>>>(counts, offsets, nb, NC);
  scatter_kernel<<<NE/256, 256, 0, stream>>>(receivers, offsets, cursor, edge_sorted);

  long long chunk_edges_max = NE/NC + 4096;
  int gA  = (int)((chunk_edges_max + 63)/64);
  int gTP = (int)((chunk_edges_max*8 + 255)/256);
  int gSO = (NN + 15)/16;
  for (int ci = 0; ci < NC; ++ci){
    edge_mix_kernel<<<gA, 64, 0, stream>>>(vectors, senders, edge_sorted,
                                           offsets, nb, Wm0p, Wm1p, Wm2p,
                                           ci, plane_stride, mixb, ylm, sedge);
    tp_kernel<<<gTP, 256, 0, stream>>>(offsets, nb, mtabh, cgbuf, mixb, ylm,
                                       sedge, ci, plane_stride, msgb);
    seg_out_kernel<<<gSO, 256, 0, stream>>>(offsets, nb, msgb, node_feats,
                                            species, Wd0, Wd1, Wd2,
                                            Wsk0, Wsk1, Wsk2, ci, out);
  }
}